// Round 4
// baseline (384.124 us; speedup 1.0000x reference)
//
#include <hip/hip_runtime.h>

typedef float        f32x4  __attribute__((ext_vector_type(4)));
typedef float        f32x16 __attribute__((ext_vector_type(16)));
typedef unsigned int u32x4  __attribute__((ext_vector_type(4)));
typedef unsigned int u32x2  __attribute__((ext_vector_type(2)));
typedef int          i32x2  __attribute__((ext_vector_type(2)));
typedef __bf16       bf16x8 __attribute__((ext_vector_type(8)));

#define DEVFN static __device__ __forceinline__

DEVFN unsigned short f2bf(float f){
  unsigned u = __builtin_bit_cast(unsigned, f);
  u += 0x7FFFu + ((u >> 16) & 1u);            // RNE
  return (unsigned short)(u >> 16);
}
DEVFN unsigned cvtpk(float a, float b){       // dst.lo=bf16(a), dst.hi=bf16(b)
  unsigned r;
  asm("v_cvt_pk_bf16_f32 %0, %1, %2" : "=v"(r) : "v"(a), "v"(b));
  return r;
}
DEVFN bf16x8 as_bf(u32x4 v){ union{u32x4 u; bf16x8 b;} x; x.u=v; return x.b; }

// x' = {x.lo31, y.lo31}; y' = {x.hi31, y.hi31}
DEVFN void plswap(unsigned &x, unsigned &y, int h){
#if __has_builtin(__builtin_amdgcn_permlane32_swap)
  i32x2 r = __builtin_amdgcn_permlane32_swap((int)x, (int)y, false, false);
  x = (unsigned)r[0]; y = (unsigned)r[1];
#else
  unsigned ox = (unsigned)__shfl_xor((int)x, 32);
  unsigned oy = (unsigned)__shfl_xor((int)y, 32);
  unsigned nx = h ? oy : x;
  unsigned ny = h ? y  : ox;
  x = nx; y = ny;
#endif
}

DEVFN void gload16(const char* src, char* lds){
  __builtin_amdgcn_global_load_lds(
      (__attribute__((address_space(1))) void*)src,
      (__attribute__((address_space(3))) void*)lds, 16, 0, 0);
}

constexpr int BB = 16, NQ = 2048, NK = 2048, F = 512, D = 256, FV = 512;

// ---------------- projection + row l2norm ---------------- (unchanged, known-good)
template<int KD, int ND, bool TR>
__global__ __launch_bounds__(256,2) void proj_kernel(const float* __restrict__ X,
                                                     const float* __restrict__ W,
                                                     unsigned short* __restrict__ Y)
{
  constexpr int NW = ND/4;
  constexpr int AF = TR ? 8 : 2;
  constexpr int BF = TR ? 2 : NW/16;
  __shared__ __align__(16) char xsm[32*80];
  __shared__ __align__(16) char wsm[ND*80];
  __shared__ float wsum[4][32];
  const int tid = threadIdx.x;
  const int lane = tid & 63;
  const int wid = tid >> 6;
  const int q16 = lane & 15;
  const int g = lane >> 4;
  const int row0 = blockIdx.x * 32;
  const int rX = tid >> 3, cX = (tid & 7) * 4;

  f32x4 z4 = {0.f,0.f,0.f,0.f};
  f32x4 acc[AF][BF];
  #pragma unroll
  for (int i=0;i<AF;i++){
    #pragma unroll
    for (int j=0;j<BF;j++) acc[i][j] = z4;
  }

  for (int k0 = 0; k0 < KD; k0 += 32){
    {
      f32x4 v = *(const f32x4*)(X + (size_t)(row0+rX)*KD + k0 + cX);
      u32x2 p; p[0]=cvtpk(v[0],v[1]); p[1]=cvtpk(v[2],v[3]);
      *(u32x2*)(xsm + rX*80 + cX*2) = p;
    }
    #pragma unroll
    for (int j=0;j<ND/32;j++){
      int r = j*32 + rX;
      f32x4 v = *(const f32x4*)(W + (size_t)r*KD + k0 + cX);
      u32x2 p; p[0]=cvtpk(v[0],v[1]); p[1]=cvtpk(v[2],v[3]);
      *(u32x2*)(wsm + r*80 + cX*2) = p;
    }
    __syncthreads();
    if constexpr (!TR){
      bf16x8 a[2], bb[BF];
      #pragma unroll
      for (int mi=0;mi<2;mi++)  a[mi]  = as_bf(*(const u32x4*)(xsm + (16*mi+q16)*80 + g*16));
      #pragma unroll
      for (int ni=0;ni<BF;ni++) bb[ni] = as_bf(*(const u32x4*)(wsm + (wid*NW + 16*ni + q16)*80 + g*16));
      #pragma unroll
      for (int mi=0;mi<2;mi++){
        #pragma unroll
        for (int ni=0;ni<BF;ni++)
          acc[mi][ni] = __builtin_amdgcn_mfma_f32_16x16x32_bf16(a[mi], bb[ni], acc[mi][ni], 0,0,0);
      }
    } else {
      bf16x8 a[8], bb[2];
      #pragma unroll
      for (int ai=0;ai<8;ai++) a[ai] = as_bf(*(const u32x4*)(wsm + (wid*NW + 16*ai + q16)*80 + g*16));
      #pragma unroll
      for (int ci=0;ci<2;ci++) bb[ci] = as_bf(*(const u32x4*)(xsm + (16*ci+q16)*80 + g*16));
      #pragma unroll
      for (int ai=0;ai<8;ai++){
        #pragma unroll
        for (int ci=0;ci<2;ci++)
          acc[ai][ci] = __builtin_amdgcn_mfma_f32_16x16x32_bf16(a[ai], bb[ci], acc[ai][ci], 0,0,0);
      }
    }
    __syncthreads();
  }

  if constexpr (!TR){
    float part[2][4];
    #pragma unroll
    for (int mi=0;mi<2;mi++){
      #pragma unroll
      for (int r=0;r<4;r++){
        float s=0.f;
        #pragma unroll
        for (int ni=0;ni<BF;ni++){ float v=acc[mi][ni][r]; s += v*v; }
        part[mi][r]=s;
      }
    }
    #pragma unroll
    for (int m=1;m<16;m<<=1){
      #pragma unroll
      for (int mi=0;mi<2;mi++){
        #pragma unroll
        for (int r=0;r<4;r++) part[mi][r] += __shfl_xor(part[mi][r], m);
      }
    }
    if (q16 == 0){
      #pragma unroll
      for (int mi=0;mi<2;mi++){
        #pragma unroll
        for (int r=0;r<4;r++) wsum[wid][16*mi + 4*g + r] = part[mi][r];
      }
    }
    __syncthreads();
    #pragma unroll
    for (int mi=0;mi<2;mi++){
      #pragma unroll
      for (int r=0;r<4;r++){
        int m = 16*mi + 4*g + r;
        float tot = wsum[0][m]+wsum[1][m]+wsum[2][m]+wsum[3][m];
        float inv = 1.f / fmaxf(sqrtf(tot), 1e-12f);
        #pragma unroll
        for (int ni=0;ni<BF;ni++){
          int col = wid*NW + 16*ni + q16;
          Y[(size_t)(row0+m)*ND + col] = f2bf(acc[mi][ni][r]*inv);
        }
      }
    }
  } else {
    float pp[2];
    #pragma unroll
    for (int ci=0;ci<2;ci++){
      float s=0.f;
      #pragma unroll
      for (int ai=0;ai<8;ai++){
        #pragma unroll
        for (int r=0;r<4;r++){ float v=acc[ai][ci][r]; s += v*v; }
      }
      pp[ci]=s;
    }
    #pragma unroll
    for (int ci=0;ci<2;ci++){
      pp[ci] += __shfl_xor(pp[ci],16);
      pp[ci] += __shfl_xor(pp[ci],32);
    }
    if (lane < 16){ wsum[wid][lane] = pp[0]; wsum[wid][16+lane] = pp[1]; }
    __syncthreads();
    #pragma unroll
    for (int ci=0;ci<2;ci++){
      int m = 16*ci + q16;
      float tot = wsum[0][m]+wsum[1][m]+wsum[2][m]+wsum[3][m];
      float inv = 1.f / fmaxf(sqrtf(tot), 1e-12f);
      int grow = row0 + m;
      int b = grow >> 11;
      int kv = grow & 2047;
      #pragma unroll
      for (int ai=0;ai<8;ai++){
        #pragma unroll
        for (int r=0;r<4;r++){
          int n = wid*NW + 16*ai + 4*g + r;
          Y[((size_t)b*FV + n)*NK + kv] = f2bf(acc[ai][ci][r]*inv);
        }
      }
    }
  }
}

// ---------------- fused attention (v4: 64q waves, 0.5KB/mfma, MFMA-bound) --------
// 256 blocks = 16 b x 8 qblk(256 q) x 2 fvblk(256 fv). 256 thr = 4 waves x 64 q.
// kv-tile 64 (2 sub-tiles of 32), double-buffered frag-major LDS, 1 barrier/tile.
// Per wave: Q (64q) in 32 reg-frags; each K/V frag read feeds 2 MFMAs.
__global__ __launch_bounds__(256,1) void attn_kernel(const float* __restrict__ query,
    const unsigned short* __restrict__ wq, const unsigned short* __restrict__ wk,
    const unsigned short* __restrict__ wvt, float* __restrict__ out)
{
  // K dbuf 2x32K @0 | V dbuf 2x32K @65536 ; epilogue reuses 16KB/wave
  __shared__ __align__(16) char smem[131072];
  const int tid = threadIdx.x, lane = tid & 63, wid = tid >> 6;
  const int l31 = lane & 31, h = lane >> 5;
  const int bid = blockIdx.x;
  const int lb = (bid & 7)*32 + (bid >> 3);   // XCD chunk swizzle, 256 = 8*32 bijective
  const int b = lb >> 4;
  const int fvblk = (lb >> 3) & 1;
  const int qblk = lb & 7;
  const int q0w = qblk*256 + wid*64;          // wave's q rows: q0w .. q0w+63

  const char* wk_b  = (const char*)(wk  + (size_t)b*NK*D);
  const char* wvt_b = (const char*)(wvt + ((size_t)b*FV + fvblk*256)*NK);
  // staging source bases (lane-resolved)
  const char* ksrc = wk_b + (size_t)l31*512 + h*16;    // + kv*512 + c*32
  const char* vsrc = wvt_b + (size_t)l31*4096 + h*16;  // + fc*131072 + kv*2 + kh*32

  // frag id fi in [0,32): K: sub=fi>>4, c=fi&15 ; V: sub=fi>>4, fc=(fi>>1)&7, kh=fi&1
  #define STAGE(T, CUR) do{                                                   \
    char* kb_ = smem + (CUR)*32768;                                           \
    char* vb_ = smem + 65536 + (CUR)*32768;                                   \
    size_t ko_ = (size_t)(T)*32768, vo_ = (size_t)(T)*128;                    \
    _Pragma("unroll")                                                         \
    for (int j=0;j<8;j++){                                                    \
      int fi = wid*8 + j;                                                     \
      int sub = fi>>4, c = fi&15;                                             \
      gload16(ksrc + ko_ + sub*16384 + c*32, kb_ + fi*1024);                  \
      int fc = (fi>>1)&7, kh = fi&1;                                          \
      gload16(vsrc + vo_ + (size_t)fc*131072 + sub*64 + kh*32, vb_ + fi*1024);\
    }                                                                         \
  }while(0)

  STAGE(0, 0);

  // Q hoist: two q-slices (A: q0w+l31, B: q0w+32+l31), 16 c-frags each
  bf16x8 qfA[16], qfB[16];
  {
    const char* qa = (const char*)(wq + ((size_t)b*NQ + q0w      + l31)*D);
    const char* qb = (const char*)(wq + ((size_t)b*NQ + q0w + 32 + l31)*D);
    #pragma unroll
    for (int c=0;c<16;c++){
      qfA[c] = as_bf(*(const u32x4*)(qa + c*32 + h*16));
      qfB[c] = as_bf(*(const u32x4*)(qb + c*32 + h*16));
    }
  }

  f32x16 z16;
  #pragma unroll
  for (int i=0;i<16;i++) z16[i]=0.f;
  f32x16 oA[8], oB[8];
  #pragma unroll
  for (int i=0;i<8;i++){ oA[i]=z16; oB[i]=z16; }
  float ssumA = 0.f, ssumB = 0.f;
  const float c1 = 0.0625f * 1.44269504088896f;   // temp*log2(e)

  __syncthreads();

  for (int t = 0; t < 32; ++t){
    const int cur = t & 1;
    if (t < 31) STAGE(t+1, cur^1);
    const char* kb = smem + cur*32768;
    const char* vb = smem + 65536 + cur*32768;

    #pragma unroll
    for (int sub=0; sub<2; ++sub){
      // S^T[kv 32][q 32] x2 : each K-frag feeds both q-slices
      f32x16 S0 = z16, S1 = z16;
      __builtin_amdgcn_s_setprio(1);
      #pragma unroll
      for (int c=0;c<16;c++){
        bf16x8 a = as_bf(*(const u32x4*)(kb + (sub*16+c)*1024 + lane*16));
        S0 = __builtin_amdgcn_mfma_f32_32x32x16_bf16(a, qfA[c], S0, 0,0,0);
        S1 = __builtin_amdgcn_mfma_f32_32x32x16_bf16(a, qfB[c], S1, 0,0,0);
      }
      __builtin_amdgcn_s_setprio(0);

      // fixed-max softmax numerators (cosine logits <= 1/16)
      float pA[16], pB[16]; float partA = 0.f, partB = 0.f;
      #pragma unroll
      for (int r=0;r<16;r++){
        pA[r] = exp2f((S0[r]-1.0f)*c1); partA += pA[r];
        pB[r] = exp2f((S1[r]-1.0f)*c1); partB += pB[r];
      }
      ssumA += partA; ssumB += partB;

      // T12: C/D -> B-frags in-register
      unsigned ka[8], kbp[8];
      #pragma unroll
      for (int j=0;j<8;j++){ ka[j] = cvtpk(pA[2*j], pA[2*j+1]); kbp[j] = cvtpk(pB[2*j], pB[2*j+1]); }
      plswap(ka[0], ka[2], h);  plswap(ka[1], ka[3], h);
      plswap(ka[4], ka[6], h);  plswap(ka[5], ka[7], h);
      plswap(kbp[0], kbp[2], h); plswap(kbp[1], kbp[3], h);
      plswap(kbp[4], kbp[6], h); plswap(kbp[5], kbp[7], h);
      u32x4 wA0 = {ka[0],ka[1],ka[2],ka[3]},   wA1 = {ka[4],ka[5],ka[6],ka[7]};
      u32x4 wB0 = {kbp[0],kbp[1],kbp[2],kbp[3]}, wB1 = {kbp[4],kbp[5],kbp[6],kbp[7]};
      bf16x8 pfA0 = as_bf(wA0), pfA1 = as_bf(wA1);
      bf16x8 pfB0 = as_bf(wB0), pfB1 = as_bf(wB1);

      // O^T += Vt-frag x P-frag ; each V-frag feeds both q-slices
      __builtin_amdgcn_s_setprio(1);
      #pragma unroll
      for (int f=0; f<16; ++f){
        bf16x8 a = as_bf(*(const u32x4*)(vb + (sub*16+f)*1024 + lane*16));
        oA[f>>1] = __builtin_amdgcn_mfma_f32_32x32x16_bf16(a, (f&1)? pfA1 : pfA0, oA[f>>1], 0,0,0);
        oB[f>>1] = __builtin_amdgcn_mfma_f32_32x32x16_bf16(a, (f&1)? pfB1 : pfB0, oB[f>>1], 0,0,0);
      }
      __builtin_amdgcn_s_setprio(0);
    }
    __syncthreads();
  }
  #undef STAGE

  // epilogue: per q-slice: scale by 1/ssum, LDS-transpose 128-fv halves, +query, store
  ssumA += __shfl_xor(ssumA, 32);
  ssumB += __shfl_xor(ssumB, 32);
  const float invA = 1.f/ssumA, invB = 1.f/ssumB;
  #pragma unroll
  for (int i=0;i<8;i++){
    #pragma unroll
    for (int r=0;r<16;r++){ oA[i][r] *= invA; oB[i][r] *= invB; }
  }

  char* wsc = smem + wid*16384;   // [32 q][128 fv] f32, XOR-swizzled (post-barrier reuse)
  union U16 { f32x16 v; f32x4 q4[4]; };
  const int swz = (l31 & 7) << 4;
  #pragma unroll
  for (int s=0; s<2; ++s){
    const int qs = q0w + s*32;
    #pragma unroll
    for (int hf=0; hf<2; ++hf){
      // write 4 frags (fv 128) into scratch: lane = q col, rows via reg map
      #pragma unroll
      for (int fc2=0; fc2<4; ++fc2){
        U16 u; u.v = s ? oB[hf*4+fc2] : oA[hf*4+fc2];
        #pragma unroll
        for (int k=0;k<4;k++){
          // fv-local byte = fc2*128 + k*32 + h*16 ; q col = l31
          *(f32x4*)(wsc + l31*512 + ((fc2*128 + k*32 + h*16) ^ swz)) = u.q4[k];
        }
      }
      // read back coalesced: 16 passes of [2 q][128 fv]
      #pragma unroll
      for (int p=0;p<16;p++){
        int qr = p*2 + h;
        f32x4 v = *(const f32x4*)(wsc + qr*512 + ((l31*16) ^ ((qr&7)<<4)));
        size_t row = (size_t)b*NQ + qs + qr;
        int col = fvblk*256 + hf*128 + l31*4;
        f32x4 qv = *(const f32x4*)(query + row*F + col);
        #pragma unroll
        for (int e=0;e<4;e++) v[e] += qv[e];
        *(f32x4*)(out + row*F + col) = v;
      }
    }
  }
}

extern "C" void kernel_launch(void* const* d_in, const int* in_sizes, int n_in,
                              void* d_out, int out_size, void* d_ws, size_t ws_size,
                              hipStream_t stream)
{
  const float* query = (const float*)d_in[0];
  const float* key   = (const float*)d_in[1];
  const float* value = (const float*)d_in[2];
  const float* WQ    = (const float*)d_in[3];
  const float* WK    = (const float*)d_in[4];
  const float* WV    = (const float*)d_in[5];
  float* out = (float*)d_out;

  unsigned short* wq  = (unsigned short*)d_ws;              // [B*NQ][256] bf16, 16MB
  unsigned short* wk  = wq + (size_t)BB*NQ*D;               // [B*NK][256] bf16, 16MB
  unsigned short* wvt = wk + (size_t)BB*NK*D;               // [B][512][NK] bf16, 32MB

  dim3 blk(256);
  proj_kernel<512,256,false><<<1024, blk, 0, stream>>>(query, WQ, wq);
  proj_kernel<256,256,false><<<1024, blk, 0, stream>>>(key,   WK, wk);
  proj_kernel<256,512,true ><<<1024, blk, 0, stream>>>(value, WV, wvt);
  attn_kernel<<<256, blk, 0, stream>>>(query, wq, wk, wvt, out);
}

// Round 5
// 250.535 us; speedup vs baseline: 1.5332x; 1.5332x over previous
//
#include <hip/hip_runtime.h>

typedef float        f32x4  __attribute__((ext_vector_type(4)));
typedef float        f32x16 __attribute__((ext_vector_type(16)));
typedef unsigned int u32x4  __attribute__((ext_vector_type(4)));
typedef unsigned int u32x2  __attribute__((ext_vector_type(2)));
typedef int          i32x2  __attribute__((ext_vector_type(2)));
typedef __bf16       bf16x8 __attribute__((ext_vector_type(8)));

#define DEVFN static __device__ __forceinline__

DEVFN unsigned short f2bf(float f){
  unsigned u = __builtin_bit_cast(unsigned, f);
  u += 0x7FFFu + ((u >> 16) & 1u);            // RNE
  return (unsigned short)(u >> 16);
}
DEVFN unsigned cvtpk(float a, float b){       // dst.lo=bf16(a), dst.hi=bf16(b)
  unsigned r;
  asm("v_cvt_pk_bf16_f32 %0, %1, %2" : "=v"(r) : "v"(a), "v"(b));
  return r;
}
DEVFN float exp2_hw(float x){                 // guaranteed single v_exp_f32
  float r;
  asm("v_exp_f32 %0, %1" : "=v"(r) : "v"(x));
  return r;
}
DEVFN bf16x8 as_bf(u32x4 v){ union{u32x4 u; bf16x8 b;} x; x.u=v; return x.b; }

// x' = {x.lo31, y.lo31}; y' = {x.hi31, y.hi31}
DEVFN void plswap(unsigned &x, unsigned &y, int h){
#if __has_builtin(__builtin_amdgcn_permlane32_swap)
  i32x2 r = __builtin_amdgcn_permlane32_swap((int)x, (int)y, false, false);
  x = (unsigned)r[0]; y = (unsigned)r[1];
#else
  unsigned ox = (unsigned)__shfl_xor((int)x, 32);
  unsigned oy = (unsigned)__shfl_xor((int)y, 32);
  unsigned nx = h ? oy : x;
  unsigned ny = h ? y  : ox;
  x = nx; y = ny;
#endif
}

DEVFN void gload16(const char* src, char* lds){
  __builtin_amdgcn_global_load_lds(
      (__attribute__((address_space(1))) void*)src,
      (__attribute__((address_space(3))) void*)lds, 16, 0, 0);
}

constexpr int BB = 16, NQ = 2048, NK = 2048, F = 512, D = 256, FV = 512;

// ---------------- projection + row l2norm ----------------
// Y[m][n] = scale * l2norm_rows( X[m][:] . W[n][:] ), 32 rows/block.
// TR=true: write Y transposed per-batch: Yt[b][n][m%2048].
template<int KD, int ND, bool TR>
__global__ __launch_bounds__(256,2) void proj_kernel(const float* __restrict__ X,
                                                     const float* __restrict__ W,
                                                     unsigned short* __restrict__ Y,
                                                     float scale)
{
  constexpr int NW = ND/4;
  constexpr int AF = TR ? 8 : 2;
  constexpr int BF = TR ? 2 : NW/16;
  __shared__ __align__(16) char xsm[32*80];
  __shared__ __align__(16) char wsm[ND*80];
  __shared__ float wsum[4][32];
  const int tid = threadIdx.x;
  const int lane = tid & 63;
  const int wid = tid >> 6;
  const int q16 = lane & 15;
  const int g = lane >> 4;
  const int row0 = blockIdx.x * 32;
  const int rX = tid >> 3, cX = (tid & 7) * 4;

  f32x4 z4 = {0.f,0.f,0.f,0.f};
  f32x4 acc[AF][BF];
  #pragma unroll
  for (int i=0;i<AF;i++){
    #pragma unroll
    for (int j=0;j<BF;j++) acc[i][j] = z4;
  }

  for (int k0 = 0; k0 < KD; k0 += 32){
    {
      f32x4 v = *(const f32x4*)(X + (size_t)(row0+rX)*KD + k0 + cX);
      u32x2 p; p[0]=cvtpk(v[0],v[1]); p[1]=cvtpk(v[2],v[3]);
      *(u32x2*)(xsm + rX*80 + cX*2) = p;
    }
    #pragma unroll
    for (int j=0;j<ND/32;j++){
      int r = j*32 + rX;
      f32x4 v = *(const f32x4*)(W + (size_t)r*KD + k0 + cX);
      u32x2 p; p[0]=cvtpk(v[0],v[1]); p[1]=cvtpk(v[2],v[3]);
      *(u32x2*)(wsm + r*80 + cX*2) = p;
    }
    __syncthreads();
    if constexpr (!TR){
      bf16x8 a[2], bb[BF];
      #pragma unroll
      for (int mi=0;mi<2;mi++)  a[mi]  = as_bf(*(const u32x4*)(xsm + (16*mi+q16)*80 + g*16));
      #pragma unroll
      for (int ni=0;ni<BF;ni++) bb[ni] = as_bf(*(const u32x4*)(wsm + (wid*NW + 16*ni + q16)*80 + g*16));
      #pragma unroll
      for (int mi=0;mi<2;mi++){
        #pragma unroll
        for (int ni=0;ni<BF;ni++)
          acc[mi][ni] = __builtin_amdgcn_mfma_f32_16x16x32_bf16(a[mi], bb[ni], acc[mi][ni], 0,0,0);
      }
    } else {
      bf16x8 a[8], bb[2];
      #pragma unroll
      for (int ai=0;ai<8;ai++) a[ai] = as_bf(*(const u32x4*)(wsm + (wid*NW + 16*ai + q16)*80 + g*16));
      #pragma unroll
      for (int ci=0;ci<2;ci++) bb[ci] = as_bf(*(const u32x4*)(xsm + (16*ci+q16)*80 + g*16));
      #pragma unroll
      for (int ai=0;ai<8;ai++){
        #pragma unroll
        for (int ci=0;ci<2;ci++)
          acc[ai][ci] = __builtin_amdgcn_mfma_f32_16x16x32_bf16(a[ai], bb[ci], acc[ai][ci], 0,0,0);
      }
    }
    __syncthreads();
  }

  if constexpr (!TR){
    float part[2][4];
    #pragma unroll
    for (int mi=0;mi<2;mi++){
      #pragma unroll
      for (int r=0;r<4;r++){
        float s=0.f;
        #pragma unroll
        for (int ni=0;ni<BF;ni++){ float v=acc[mi][ni][r]; s += v*v; }
        part[mi][r]=s;
      }
    }
    #pragma unroll
    for (int m=1;m<16;m<<=1){
      #pragma unroll
      for (int mi=0;mi<2;mi++){
        #pragma unroll
        for (int r=0;r<4;r++) part[mi][r] += __shfl_xor(part[mi][r], m);
      }
    }
    if (q16 == 0){
      #pragma unroll
      for (int mi=0;mi<2;mi++){
        #pragma unroll
        for (int r=0;r<4;r++) wsum[wid][16*mi + 4*g + r] = part[mi][r];
      }
    }
    __syncthreads();
    #pragma unroll
    for (int mi=0;mi<2;mi++){
      #pragma unroll
      for (int r=0;r<4;r++){
        int m = 16*mi + 4*g + r;
        float tot = wsum[0][m]+wsum[1][m]+wsum[2][m]+wsum[3][m];
        float inv = scale / fmaxf(sqrtf(tot), 1e-12f);
        #pragma unroll
        for (int ni=0;ni<BF;ni++){
          int col = wid*NW + 16*ni + q16;
          Y[(size_t)(row0+m)*ND + col] = f2bf(acc[mi][ni][r]*inv);
        }
      }
    }
  } else {
    float pp[2];
    #pragma unroll
    for (int ci=0;ci<2;ci++){
      float s=0.f;
      #pragma unroll
      for (int ai=0;ai<8;ai++){
        #pragma unroll
        for (int r=0;r<4;r++){ float v=acc[ai][ci][r]; s += v*v; }
      }
      pp[ci]=s;
    }
    #pragma unroll
    for (int ci=0;ci<2;ci++){
      pp[ci] += __shfl_xor(pp[ci],16);
      pp[ci] += __shfl_xor(pp[ci],32);
    }
    if (lane < 16){ wsum[wid][lane] = pp[0]; wsum[wid][16+lane] = pp[1]; }
    __syncthreads();
    #pragma unroll
    for (int ci=0;ci<2;ci++){
      int m = 16*ci + q16;
      float tot = wsum[0][m]+wsum[1][m]+wsum[2][m]+wsum[3][m];
      float inv = scale / fmaxf(sqrtf(tot), 1e-12f);
      int grow = row0 + m;
      int b = grow >> 11;
      int kv = grow & 2047;
      #pragma unroll
      for (int ai=0;ai<8;ai++){
        #pragma unroll
        for (int r=0;r<4;r++){
          int n = wid*NW + 16*ai + 4*g + r;
          Y[((size_t)b*FV + n)*NK + kv] = f2bf(acc[ai][ci][r]*inv);
        }
      }
    }
  }
}

// ---------------- fused attention (v5: 8 waves = 4 q-slices x 2 fv-halves) --------
// 256 blocks = 16 b x 16 qblk(128 q). 512 thr = 8 waves; wave = (qs, fvh):
// 32 q rows (slice qs), 256 fv cols (half fvh). QK duplicated across fv-halves
// (137 GF total). kv-tile 32, dbuf frag-major LDS (96KB), 1 barrier/tile.
// wq pre-scaled by temp*log2e so p = exp2(S) directly.
__global__ __launch_bounds__(512,2) void attn_kernel(const float* __restrict__ query,
    const unsigned short* __restrict__ wq, const unsigned short* __restrict__ wk,
    const unsigned short* __restrict__ wvt, float* __restrict__ out)
{
  // K dbuf 2x16K @0 | V dbuf 2x32K @32768 ; total 96KB. Epilogue reuses 64KB.
  __shared__ __align__(16) char smem[98304];
  const int tid = threadIdx.x, lane = tid & 63, wid = tid >> 6;
  const int l31 = lane & 31, h = lane >> 5;
  const int qs = wid & 3, fvh = wid >> 2;
  const int bid = blockIdx.x;
  const int lb = (bid & 7)*32 + (bid >> 3);   // XCD chunk swizzle, 256 = 8*32 bijective
  const int b = lb >> 4;
  const int qblk = lb & 15;
  const int q0 = qblk*128;

  const char* wk_b  = (const char*)(wk  + (size_t)b*NK*D);
  const char* wvt_b = (const char*)(wvt + (size_t)b*FV*NK);
  // staging source bases (lane-resolved)
  const char* ksrc  = wk_b + (size_t)l31*512 + wid*64 + h*16;          // frags 2w, 2w+1
  const char* vsrcA = wvt_b + (size_t)(wid*2)*131072 + (size_t)l31*4096 + h*16;
  const char* vsrcB = vsrcA + 131072;

  #define STAGE(T, CUR) do{                                           \
    char* kb_ = smem + (CUR)*16384;                                   \
    char* vb_ = smem + 32768 + (CUR)*32768;                           \
    size_t ko_ = (size_t)(T)*16384, vo_ = (size_t)(T)*64;             \
    gload16(ksrc  + ko_,      kb_ + (2*wid  )*1024);                  \
    gload16(ksrc  + ko_ + 32, kb_ + (2*wid+1)*1024);                  \
    gload16(vsrcA + vo_,      vb_ + (4*wid  )*1024);                  \
    gload16(vsrcA + vo_ + 32, vb_ + (4*wid+1)*1024);                  \
    gload16(vsrcB + vo_,      vb_ + (4*wid+2)*1024);                  \
    gload16(vsrcB + vo_ + 32, vb_ + (4*wid+3)*1024);                  \
  }while(0)

  STAGE(0, 0);

  // Q hoist for slice qs: B-frags [16 c][32 q], lane: q=l31, d = c*16 + h*8 ..+8
  bf16x8 qf[16];
  {
    const char* qb = (const char*)(wq + ((size_t)b*NQ + q0 + qs*32 + l31)*D);
    #pragma unroll
    for (int c=0;c<16;c++) qf[c] = as_bf(*(const u32x4*)(qb + c*32 + h*16));
  }

  f32x16 z16;
  #pragma unroll
  for (int i=0;i<16;i++) z16[i]=0.f;
  f32x16 o[8];
  #pragma unroll
  for (int i=0;i<8;i++) o[i]=z16;
  float ssum = 0.f;

  __syncthreads();

  #define BODY(T, CUR) do{                                                          \
    if ((T) < 63) STAGE((T)+1, (CUR)^1);                                            \
    const char* kb = smem + (CUR)*16384;                                            \
    const char* vb = smem + 32768 + (CUR)*32768;                                    \
    f32x16 S = z16;                                                                 \
    __builtin_amdgcn_s_setprio(1);                                                  \
    _Pragma("unroll")                                                               \
    for (int c=0;c<16;c++){                                                         \
      bf16x8 a = as_bf(*(const u32x4*)(kb + c*1024 + lane*16));                     \
      S = __builtin_amdgcn_mfma_f32_32x32x16_bf16(a, qf[c], S, 0,0,0);              \
    }                                                                               \
    __builtin_amdgcn_s_setprio(0);                                                  \
    float p[16];                                                                    \
    _Pragma("unroll")                                                               \
    for (int r=0;r<16;r++) p[r] = exp2_hw(S[r]);                                    \
    float s2[8];                                                                    \
    _Pragma("unroll")                                                               \
    for (int j=0;j<8;j++) s2[j] = p[2*j] + p[2*j+1];                                \
    float s4a = (s2[0]+s2[1]) + (s2[2]+s2[3]);                                      \
    float s4b = (s2[4]+s2[5]) + (s2[6]+s2[7]);                                      \
    ssum += s4a + s4b;                                                              \
    unsigned pk[8];                                                                 \
    _Pragma("unroll")                                                               \
    for (int j=0;j<8;j++) pk[j] = cvtpk(p[2*j], p[2*j+1]);                          \
    plswap(pk[0], pk[2], h);  plswap(pk[1], pk[3], h);                              \
    plswap(pk[4], pk[6], h);  plswap(pk[5], pk[7], h);                              \
    u32x4 w0 = {pk[0],pk[1],pk[2],pk[3]}, w1 = {pk[4],pk[5],pk[6],pk[7]};           \
    bf16x8 pf0 = as_bf(w0), pf1 = as_bf(w1);                                        \
    __builtin_amdgcn_s_setprio(1);                                                  \
    _Pragma("unroll")                                                               \
    for (int u=0;u<8;u++){                                                          \
      bf16x8 a0 = as_bf(*(const u32x4*)(vb + ((fvh*8+u)*2  )*1024 + lane*16));      \
      o[u] = __builtin_amdgcn_mfma_f32_32x32x16_bf16(a0, pf0, o[u], 0,0,0);         \
      bf16x8 a1 = as_bf(*(const u32x4*)(vb + ((fvh*8+u)*2+1)*1024 + lane*16));      \
      o[u] = __builtin_amdgcn_mfma_f32_32x32x16_bf16(a1, pf1, o[u], 0,0,0);         \
    }                                                                               \
    __builtin_amdgcn_s_setprio(0);                                                  \
    __syncthreads();                                                                \
  }while(0)

  for (int tt = 0; tt < 64; tt += 2){
    BODY(tt,   0);
    BODY(tt+1, 1);
  }
  #undef BODY
  #undef STAGE

  // epilogue: scale by 1/ssum, transpose via LDS [32q][128fv] x2, +query, store.
  ssum += __shfl_xor(ssum, 32);
  const float inv = 1.f/ssum;
  #pragma unroll
  for (int i=0;i<8;i++){
    #pragma unroll
    for (int r=0;r<16;r++) o[i][r] *= inv;
  }

  char* wsc = smem + qs*16384;
  union U16 { f32x16 v; f32x4 q4[4]; };
  const int swz = (l31 & 7) << 4;
  #pragma unroll
  for (int phase=0; phase<2; ++phase){
    if (fvh == phase){
      #pragma unroll
      for (int hf=0; hf<2; ++hf){
        #pragma unroll
        for (int fc2=0; fc2<4; ++fc2){
          U16 u; u.v = o[hf*4+fc2];
          #pragma unroll
          for (int k=0;k<4;k++){
            *(f32x4*)(wsc + l31*512 + ((fc2*128 + k*32 + h*16) ^ swz)) = u.q4[k];
          }
        }
        #pragma unroll
        for (int p2=0;p2<16;p2++){
          int qr = p2*2 + h;
          f32x4 v = *(const f32x4*)(wsc + qr*512 + ((l31*16) ^ ((qr&7)<<4)));
          size_t row = (size_t)b*NQ + q0 + qs*32 + qr;
          int col = fvh*256 + hf*128 + l31*4;
          f32x4 qv = *(const f32x4*)(query + row*F + col);
          #pragma unroll
          for (int e=0;e<4;e++) v[e] += qv[e];
          *(f32x4*)(out + row*F + col) = v;
        }
      }
    }
    __syncthreads();
  }
}

extern "C" void kernel_launch(void* const* d_in, const int* in_sizes, int n_in,
                              void* d_out, int out_size, void* d_ws, size_t ws_size,
                              hipStream_t stream)
{
  const float* query = (const float*)d_in[0];
  const float* key   = (const float*)d_in[1];
  const float* value = (const float*)d_in[2];
  const float* WQ    = (const float*)d_in[3];
  const float* WK    = (const float*)d_in[4];
  const float* WV    = (const float*)d_in[5];
  float* out = (float*)d_out;

  unsigned short* wq  = (unsigned short*)d_ws;              // [B*NQ][256] bf16, 16MB
  unsigned short* wk  = wq + (size_t)BB*NQ*D;               // [B*NK][256] bf16, 16MB
  unsigned short* wvt = wk + (size_t)BB*NK*D;               // [B][512][NK] bf16, 32MB

  const float c1 = 0.0625f * 1.4426950408889634f;           // temp * log2(e)
  dim3 blk(256);
  proj_kernel<512,256,false><<<1024, blk, 0, stream>>>(query, WQ, wq, c1);
  proj_kernel<256,256,false><<<1024, blk, 0, stream>>>(key,   WK, wk, 1.0f);
  proj_kernel<256,512,true ><<<1024, blk, 0, stream>>>(value, WV, wvt, 1.0f);
  attn_kernel<<<256, dim3(512), 0, stream>>>(query, wq, wk, wvt, out);
}